// Round 4
// baseline (142.843 us; speedup 1.0000x reference)
//
#include <hip/hip_runtime.h>

typedef _Float16 half2_t __attribute__((ext_vector_type(2)));
typedef float    f4raw   __attribute__((ext_vector_type(4)));

constexpr int H  = 128;     // hidden dim
constexpr int T  = 8;       // edge types
constexpr int H4 = H / 4;   // float4 per fp32 row

__device__ __forceinline__ float dot2acc(half2_t a, half2_t b, float c) {
#if __has_builtin(__builtin_amdgcn_fdot2)
    return __builtin_amdgcn_fdot2(a, b, c, false);
#else
    return fmaf((float)a.x, (float)b.x, fmaf((float)a.y, (float)b.y, c));
#endif
}

__device__ __forceinline__ half2_t hrelu_add(half2_t a, half2_t b) {
    half2_t s = a + b;
    half2_t r;
    r.x = s.x > (_Float16)0 ? s.x : (_Float16)0;
    r.y = s.y > (_Float16)0 ? s.y : (_Float16)0;
    return r;
}

__device__ __forceinline__ float f4_get(const float4& v, int k) {
    return k == 0 ? v.x : k == 1 ? v.y : k == 2 ? v.z : v.w;
}

// ---------------- pre-pass: x fp32 -> fp16 into workspace ----------------
// Nontemporal reads: the fp32 x is never re-read; keep L2/L3 for the fp16 copy.
__global__ __launch_bounds__(256)
void cvt_x_kernel(const f4raw* __restrict__ x4, float4* __restrict__ o4, int n8) {
    int i = blockIdx.x * blockDim.x + threadIdx.x;
    if (i >= n8) return;
    f4raw p = __builtin_nontemporal_load(&x4[2 * i]);
    f4raw q = __builtin_nontemporal_load(&x4[2 * i + 1]);
    half2_t a = {(_Float16)p.x, (_Float16)p.y};
    half2_t b = {(_Float16)p.z, (_Float16)p.w};
    half2_t c = {(_Float16)q.x, (_Float16)q.y};
    half2_t d = {(_Float16)q.z, (_Float16)q.w};
    float4 o;
    o.x = __builtin_bit_cast(float, a);
    o.y = __builtin_bit_cast(float, b);
    o.z = __builtin_bit_cast(float, c);
    o.w = __builtin_bit_cast(float, d);
    o4[i] = o;
}

// ---------------- main: fp16 gather, 4 edges per 8-lane group ----------------
// Saturation test for the L2-miss path: 16 float4 gathers issued before any
// consumption (2x round-3 MLP per thread), one LDS W read serves 4 edges
// (LDS pipe halved), waves halved. launch_bounds(256,2) keeps the compiler
// from spilling to hit 8 waves/EU (round-1 failure mode).
__global__ __launch_bounds__(256, 2)
void edge_type_fp16_kernel(const float4* __restrict__ xh,
                           const int* __restrict__ eidx,
                           const float* __restrict__ W,
                           const float* __restrict__ b,
                           float* __restrict__ out,
                           int E)
{
    __shared__ half2_t sW[T * H / 2];   // 2 KB, [t][f] fp16
    for (int i = threadIdx.x; i < T * H / 2; i += blockDim.x) {
        half2_t v;
        v.x = (_Float16)W[2 * i];
        v.y = (_Float16)W[2 * i + 1];
        sW[i] = v;
    }
    __syncthreads();
    const float4* sW4 = reinterpret_cast<const float4*>(sW);  // [t*16 + j*8 + lane]

    const int lane = threadIdx.x & 7;
    const int g    = threadIdx.x >> 3;            // 0..31
    const int base = blockIdx.x * 128;            // 128 edges per block

    int  e[4], s[4], d[4];
    bool vld[4];
    #pragma unroll
    for (int k = 0; k < 4; ++k) {
        e[k]   = base + k * 32 + g;               // wave's groups -> consecutive edges
        vld[k] = e[k] < E;
        const int ec = vld[k] ? e[k] : 0;
        s[k] = eidx[ec];
        d[k] = eidx[E + ec];
    }

    // issue all 16 gathers up front
    float4 A[4][2], C[4][2];
    #pragma unroll
    for (int k = 0; k < 4; ++k) {
        const float4* xs = xh + (size_t)s[k] * 16;   // 16 float4 per fp16 row
        const float4* xd = xh + (size_t)d[k] * 16;
        #pragma unroll
        for (int j = 0; j < 2; ++j) {
            A[k][j] = xs[j * 8 + lane];              // 8 lanes -> contiguous 128B
            C[k][j] = xd[j * 8 + lane];
        }
    }

    half2_t h[4][8];                                 // 16 fp16 features per edge
    #pragma unroll
    for (int k = 0; k < 4; ++k)
        #pragma unroll
        for (int j = 0; j < 2; ++j)
            #pragma unroll
            for (int kk = 0; kk < 4; ++kk)
                h[k][j * 4 + kk] =
                    hrelu_add(__builtin_bit_cast(half2_t, f4_get(A[k][j], kk)),
                              __builtin_bit_cast(half2_t, f4_get(C[k][j], kk)));

    float p[4][T];
    #pragma unroll
    for (int k = 0; k < 4; ++k)
        #pragma unroll
        for (int t = 0; t < T; ++t) p[k][t] = 0.f;

    #pragma unroll
    for (int t = 0; t < T; ++t) {
        #pragma unroll
        for (int j = 0; j < 2; ++j) {
            float4 w = sW4[t * 16 + j * 8 + lane];   // one read serves 4 edges
            #pragma unroll
            for (int kk = 0; kk < 4; ++kk) {
                half2_t wv = __builtin_bit_cast(half2_t, f4_get(w, kk));
                #pragma unroll
                for (int k = 0; k < 4; ++k)
                    p[k][t] = dot2acc(h[k][j * 4 + kk], wv, p[k][t]);
            }
        }
    }

    const float bias = b[lane];
    // per edge: 7-shfl merge tree, lane l ends with type l's sum
    #pragma unroll
    for (int k = 0; k < 4; ++k) {
        float q[4];
        #pragma unroll
        for (int m = 0; m < 4; ++m) {
            float keep = (lane & 1) ? p[k][2 * m + 1] : p[k][2 * m];
            float send = (lane & 1) ? p[k][2 * m]     : p[k][2 * m + 1];
            q[m] = keep + __shfl_xor(send, 1);
        }
        float r2[2];
        #pragma unroll
        for (int m = 0; m < 2; ++m) {
            float keep = (lane & 2) ? q[2 * m + 1] : q[2 * m];
            float send = (lane & 2) ? q[2 * m]     : q[2 * m + 1];
            r2[m] = keep + __shfl_xor(send, 2);
        }
        float keep = (lane & 4) ? r2[1] : r2[0];
        float send = (lane & 4) ? r2[0] : r2[1];
        float r = keep + __shfl_xor(send, 4) + bias;
        if (vld[k]) __builtin_nontemporal_store(r, &out[(size_t)e[k] * T + lane]);
    }
}

// ---------------- fallback: fp32 kernel (if ws too small) ----------------
__device__ __forceinline__ float4 relu_add(float4 a, float4 c) {
    float4 h;
    h.x = fmaxf(a.x + c.x, 0.f);
    h.y = fmaxf(a.y + c.y, 0.f);
    h.z = fmaxf(a.z + c.z, 0.f);
    h.w = fmaxf(a.w + c.w, 0.f);
    return h;
}

__global__ __launch_bounds__(256, 4)
void edge_type_fp32_kernel(const float* __restrict__ x,
                           const int* __restrict__ eidx,
                           const float* __restrict__ W,
                           const float* __restrict__ b,
                           float* __restrict__ out,
                           int E)
{
    __shared__ float sW[T * H];
    for (int i = threadIdx.x; i < T * H; i += blockDim.x) sW[i] = W[i];
    __syncthreads();
    const float4* sW4 = reinterpret_cast<const float4*>(sW);

    const int lane = threadIdx.x & 7;
    const int e    = (blockIdx.x * blockDim.x + threadIdx.x) >> 3;
    if (e >= E) return;

    const int s = eidx[e];
    const int d = eidx[E + e];
    const float4* xs = reinterpret_cast<const float4*>(x) + (size_t)s * H4;
    const float4* xd = reinterpret_cast<const float4*>(x) + (size_t)d * H4;

    float p[T];
    #pragma unroll
    for (int t = 0; t < T; ++t) p[t] = 0.f;

    #pragma unroll
    for (int j = 0; j < 4; ++j) {
        const int o = j * 8 + lane;
        float4 h = relu_add(xs[o], xd[o]);
        #pragma unroll
        for (int t = 0; t < T; ++t) {
            float4 w = sW4[t * H4 + o];
            p[t] = fmaf(h.x, w.x, fmaf(h.y, w.y, fmaf(h.z, w.z, fmaf(h.w, w.w, p[t]))));
        }
    }

    float q[4];
    #pragma unroll
    for (int k = 0; k < 4; ++k) {
        float keep = (lane & 1) ? p[2 * k + 1] : p[2 * k];
        float send = (lane & 1) ? p[2 * k]     : p[2 * k + 1];
        q[k] = keep + __shfl_xor(send, 1);
    }
    float r2[2];
    #pragma unroll
    for (int k = 0; k < 2; ++k) {
        float keep = (lane & 2) ? q[2 * k + 1] : q[2 * k];
        float send = (lane & 2) ? q[2 * k]     : q[2 * k + 1];
        r2[k] = keep + __shfl_xor(send, 2);
    }
    float keep = (lane & 4) ? r2[1] : r2[0];
    float send = (lane & 4) ? r2[0] : r2[1];
    float r = keep + __shfl_xor(send, 4) + b[lane];
    __builtin_nontemporal_store(r, &out[(size_t)e * T + lane]);
}

extern "C" void kernel_launch(void* const* d_in, const int* in_sizes, int n_in,
                              void* d_out, int out_size, void* d_ws, size_t ws_size,
                              hipStream_t stream) {
    const float* x    = (const float*)d_in[0];   // [N_NODES, 128] fp32
    const int*   eidx = (const int*)d_in[1];     // [2, E] int32
    const float* W    = (const float*)d_in[2];   // [8, 128] fp32
    const float* b    = (const float*)d_in[3];   // [8] fp32
    float*       out  = (float*)d_out;           // [E, 8] fp32

    const int E  = in_sizes[1] / 2;
    const int nx = in_sizes[0];                  // node-feature element count

    const size_t need = (size_t)nx * 2;          // fp16 copy of x
    if (ws_size >= need && (nx % 8) == 0) {
        const int n8 = nx / 8;
        cvt_x_kernel<<<dim3((n8 + 255) / 256), dim3(256), 0, stream>>>(
            (const f4raw*)x, (float4*)d_ws, n8);

        const int blocks = (E + 127) / 128;      // 128 edges per block
        edge_type_fp16_kernel<<<dim3(blocks), dim3(256), 0, stream>>>(
            (const float4*)d_ws, eidx, W, b, out, E);
    } else {
        const int blocks = (E + 31) / 32;
        edge_type_fp32_kernel<<<dim3(blocks), dim3(256), 0, stream>>>(
            x, eidx, W, b, out, E);
    }
}

// Round 5
// 139.858 us; speedup vs baseline: 1.0213x; 1.0213x over previous
//
#include <hip/hip_runtime.h>

typedef _Float16 half2_t __attribute__((ext_vector_type(2)));
typedef float    f4raw   __attribute__((ext_vector_type(4)));

constexpr int H  = 128;     // hidden dim
constexpr int T  = 8;       // edge types
constexpr int H4 = H / 4;   // float4 per fp32 row

__device__ __forceinline__ float dot2acc(half2_t a, half2_t b, float c) {
#if __has_builtin(__builtin_amdgcn_fdot2)
    return __builtin_amdgcn_fdot2(a, b, c, false);
#else
    return fmaf((float)a.x, (float)b.x, fmaf((float)a.y, (float)b.y, c));
#endif
}

__device__ __forceinline__ half2_t hrelu_add(half2_t a, half2_t b) {
    half2_t s = a + b;
    half2_t r;
    r.x = s.x > (_Float16)0 ? s.x : (_Float16)0;
    r.y = s.y > (_Float16)0 ? s.y : (_Float16)0;
    return r;
}

__device__ __forceinline__ float f4_get(const float4& v, int k) {
    return k == 0 ? v.x : k == 1 ? v.y : k == 2 ? v.z : v.w;
}

// ---------------- pre-pass: x fp32 -> fp16 into workspace ----------------
// Nontemporal reads: fp32 x is never re-read; don't displace the fp16 copy.
// 77MB total traffic ~= 12us at 6.3TB/s — HBM roofline for this pass.
__global__ __launch_bounds__(256)
void cvt_x_kernel(const f4raw* __restrict__ x4, float4* __restrict__ o4, int n8) {
    int i = blockIdx.x * blockDim.x + threadIdx.x;
    if (i >= n8) return;
    f4raw p = __builtin_nontemporal_load(&x4[2 * i]);
    f4raw q = __builtin_nontemporal_load(&x4[2 * i + 1]);
    half2_t a = {(_Float16)p.x, (_Float16)p.y};
    half2_t b = {(_Float16)p.z, (_Float16)p.w};
    half2_t c = {(_Float16)q.x, (_Float16)q.y};
    half2_t d = {(_Float16)q.z, (_Float16)q.w};
    float4 o;
    o.x = __builtin_bit_cast(float, a);
    o.y = __builtin_bit_cast(float, b);
    o.z = __builtin_bit_cast(float, c);
    o.w = __builtin_bit_cast(float, d);
    o4[i] = o;
}

// ---------------- main: fp16 gather, 2 edges per 8-lane group ----------------
// Round-3 winner, reverted after round-4 saturation test: 4-edge/group (VGPR
// 72, occ 25%) and 2-edge/group (VGPR 32, occ 68%) both hit 43-44.5us with
// identical FETCH=130MB -> the random-gather miss path (~3.4TB/s on a 25.6MB
// footprint vs 4MB/XCD private L2) is saturated; this config is the cheaper
// of the two on occupancy and wins by ~1.4us.
__global__ __launch_bounds__(256, 4)
void edge_type_fp16_kernel(const float4* __restrict__ xh,
                           const int* __restrict__ eidx,
                           const float* __restrict__ W,
                           const float* __restrict__ b,
                           float* __restrict__ out,
                           int E)
{
    __shared__ half2_t sW[T * H / 2];   // 2 KB, [t][f] fp16
    for (int i = threadIdx.x; i < T * H / 2; i += blockDim.x) {
        half2_t v;
        v.x = (_Float16)W[2 * i];
        v.y = (_Float16)W[2 * i + 1];
        sW[i] = v;
    }
    __syncthreads();
    const float4* sW4 = reinterpret_cast<const float4*>(sW);  // [t*16 + j*8 + lane]

    const int lane = threadIdx.x & 7;
    const int g    = threadIdx.x >> 3;            // 0..31
    const int base = blockIdx.x * 64;
    const int e0   = base + g;                    // wave's 8 groups -> 8 consecutive edges
    const int e1   = base + 32 + g;
    const bool v0  = e0 < E, v1 = e1 < E;
    const int e0c  = v0 ? e0 : 0, e1c = v1 ? e1 : 0;

    const int s0 = eidx[e0c], d0 = eidx[E + e0c];
    const int s1 = eidx[e1c], d1 = eidx[E + e1c];

    const float4* xs0 = xh + (size_t)s0 * 16;     // 16 float4 per fp16 row
    const float4* xd0 = xh + (size_t)d0 * 16;
    const float4* xs1 = xh + (size_t)s1 * 16;
    const float4* xd1 = xh + (size_t)d1 * 16;

    half2_t h0[8], h1[8];                         // 16 fp16 features per edge
    #pragma unroll
    for (int j = 0; j < 2; ++j) {
        const int o = j * 8 + lane;               // 8 lanes -> contiguous 128B
        float4 a0 = xs0[o], c0 = xd0[o];
        float4 a1 = xs1[o], c1 = xd1[o];
        #pragma unroll
        for (int k = 0; k < 4; ++k) {
            h0[j * 4 + k] = hrelu_add(__builtin_bit_cast(half2_t, f4_get(a0, k)),
                                      __builtin_bit_cast(half2_t, f4_get(c0, k)));
            h1[j * 4 + k] = hrelu_add(__builtin_bit_cast(half2_t, f4_get(a1, k)),
                                      __builtin_bit_cast(half2_t, f4_get(c1, k)));
        }
    }

    float p0[T], p1[T];
    #pragma unroll
    for (int t = 0; t < T; ++t) { p0[t] = 0.f; p1[t] = 0.f; }

    #pragma unroll
    for (int t = 0; t < T; ++t) {
        #pragma unroll
        for (int j = 0; j < 2; ++j) {
            float4 w = sW4[t * 16 + j * 8 + lane];   // one LDS read, both edges
            #pragma unroll
            for (int k = 0; k < 4; ++k) {
                half2_t wv = __builtin_bit_cast(half2_t, f4_get(w, k));
                p0[t] = dot2acc(h0[j * 4 + k], wv, p0[t]);
                p1[t] = dot2acc(h1[j * 4 + k], wv, p1[t]);
            }
        }
    }

    // 8-lane merge tree: 7 shfls per edge, lane l ends with type l's sum.
    float q0[4], q1[4];
    #pragma unroll
    for (int k = 0; k < 4; ++k) {
        float keep0 = (lane & 1) ? p0[2 * k + 1] : p0[2 * k];
        float send0 = (lane & 1) ? p0[2 * k]     : p0[2 * k + 1];
        q0[k] = keep0 + __shfl_xor(send0, 1);
        float keep1 = (lane & 1) ? p1[2 * k + 1] : p1[2 * k];
        float send1 = (lane & 1) ? p1[2 * k]     : p1[2 * k + 1];
        q1[k] = keep1 + __shfl_xor(send1, 1);
    }
    float r0[2], r1[2];
    #pragma unroll
    for (int k = 0; k < 2; ++k) {
        float keep0 = (lane & 2) ? q0[2 * k + 1] : q0[2 * k];
        float send0 = (lane & 2) ? q0[2 * k]     : q0[2 * k + 1];
        r0[k] = keep0 + __shfl_xor(send0, 2);
        float keep1 = (lane & 2) ? q1[2 * k + 1] : q1[2 * k];
        float send1 = (lane & 2) ? q1[2 * k]     : q1[2 * k + 1];
        r1[k] = keep1 + __shfl_xor(send1, 2);
    }
    const float bias = b[lane];
    {
        float keep = (lane & 4) ? r0[1] : r0[0];
        float send = (lane & 4) ? r0[0] : r0[1];
        float r = keep + __shfl_xor(send, 4) + bias;
        if (v0) __builtin_nontemporal_store(r, &out[(size_t)e0 * T + lane]);
    }
    {
        float keep = (lane & 4) ? r1[1] : r1[0];
        float send = (lane & 4) ? r1[0] : r1[1];
        float r = keep + __shfl_xor(send, 4) + bias;
        if (v1) __builtin_nontemporal_store(r, &out[(size_t)e1 * T + lane]);
    }
}

// ---------------- fallback: fp32 kernel (if ws too small) ----------------
__device__ __forceinline__ float4 relu_add(float4 a, float4 c) {
    float4 h;
    h.x = fmaxf(a.x + c.x, 0.f);
    h.y = fmaxf(a.y + c.y, 0.f);
    h.z = fmaxf(a.z + c.z, 0.f);
    h.w = fmaxf(a.w + c.w, 0.f);
    return h;
}

__global__ __launch_bounds__(256, 4)
void edge_type_fp32_kernel(const float* __restrict__ x,
                           const int* __restrict__ eidx,
                           const float* __restrict__ W,
                           const float* __restrict__ b,
                           float* __restrict__ out,
                           int E)
{
    __shared__ float sW[T * H];
    for (int i = threadIdx.x; i < T * H; i += blockDim.x) sW[i] = W[i];
    __syncthreads();
    const float4* sW4 = reinterpret_cast<const float4*>(sW);

    const int lane = threadIdx.x & 7;
    const int e    = (blockIdx.x * blockDim.x + threadIdx.x) >> 3;
    if (e >= E) return;

    const int s = eidx[e];
    const int d = eidx[E + e];
    const float4* xs = reinterpret_cast<const float4*>(x) + (size_t)s * H4;
    const float4* xd = reinterpret_cast<const float4*>(x) + (size_t)d * H4;

    float p[T];
    #pragma unroll
    for (int t = 0; t < T; ++t) p[t] = 0.f;

    #pragma unroll
    for (int j = 0; j < 4; ++j) {
        const int o = j * 8 + lane;
        float4 h = relu_add(xs[o], xd[o]);
        #pragma unroll
        for (int t = 0; t < T; ++t) {
            float4 w = sW4[t * H4 + o];
            p[t] = fmaf(h.x, w.x, fmaf(h.y, w.y, fmaf(h.z, w.z, fmaf(h.w, w.w, p[t]))));
        }
    }

    float q[4];
    #pragma unroll
    for (int k = 0; k < 4; ++k) {
        float keep = (lane & 1) ? p[2 * k + 1] : p[2 * k];
        float send = (lane & 1) ? p[2 * k]     : p[2 * k + 1];
        q[k] = keep + __shfl_xor(send, 1);
    }
    float r2[2];
    #pragma unroll
    for (int k = 0; k < 2; ++k) {
        float keep = (lane & 2) ? q[2 * k + 1] : q[2 * k];
        float send = (lane & 2) ? q[2 * k]     : q[2 * k + 1];
        r2[k] = keep + __shfl_xor(send, 2);
    }
    float keep = (lane & 4) ? r2[1] : r2[0];
    float send = (lane & 4) ? r2[0] : r2[1];
    float r = keep + __shfl_xor(send, 4) + b[lane];
    __builtin_nontemporal_store(r, &out[(size_t)e * T + lane]);
}

extern "C" void kernel_launch(void* const* d_in, const int* in_sizes, int n_in,
                              void* d_out, int out_size, void* d_ws, size_t ws_size,
                              hipStream_t stream) {
    const float* x    = (const float*)d_in[0];   // [N_NODES, 128] fp32
    const int*   eidx = (const int*)d_in[1];     // [2, E] int32
    const float* W    = (const float*)d_in[2];   // [8, 128] fp32
    const float* b    = (const float*)d_in[3];   // [8] fp32
    float*       out  = (float*)d_out;           // [E, 8] fp32

    const int E  = in_sizes[1] / 2;
    const int nx = in_sizes[0];                  // node-feature element count

    const size_t need = (size_t)nx * 2;          // fp16 copy of x
    if (ws_size >= need && (nx % 8) == 0) {
        const int n8 = nx / 8;
        cvt_x_kernel<<<dim3((n8 + 255) / 256), dim3(256), 0, stream>>>(
            (const f4raw*)x, (float4*)d_ws, n8);

        const int blocks = (E + 63) / 64;        // 64 edges per block
        edge_type_fp16_kernel<<<dim3(blocks), dim3(256), 0, stream>>>(
            (const float4*)d_ws, eidx, W, b, out, E);
    } else {
        const int blocks = (E + 31) / 32;
        edge_type_fp32_kernel<<<dim3(blocks), dim3(256), 0, stream>>>(
            x, eidx, W, b, out, E);
    }
}